// Round 3
// baseline (673.634 us; speedup 1.0000x reference)
//
#include <hip/hip_runtime.h>
#include <stdint.h>

// Self-attention, B=8, S=2048, D=1024, fp32 in/out, bf16 MFMA compute.
//
// Pipeline:
//   1. cvt: x -> xb (bf16); Wq/Wk/Wv -> Wb (bf16, one fused launch)
//   2. k_qkv  : Q/K = xb @ W^T + b     (z=0,1)    GEMM_BT, bf16 out
//      k_qkvV : Vt = (xb @ Wv^T + bv)^T (direct transposed epilogue)
//   3. k_scores: U = exp((Q @ K^T)/32)  bf16 (scores bounded, no max-sub)
//   4. k_rowsum: linv[b,m] = 1 / sum_k U
//   5. k_pv   : out = (U @ Vt^T) * linv  (fp32 out)
//
// R3: B-operand loaded global->VGPR (skips LDS; B-tiles are L2/L1-resident
// thanks to the XCD swizzle). Only A goes through LDS via global_load_lds.
// This halves LDS traffic (prior model: LDS ~18K cyc/block vs MFMA 9.9K) and
// halves the vmcnt-drain at the barrier. Vt produced directly by the V-slice
// epilogue (acc holds 4 consecutive rows per lane -> packed bf16x4 store is
// contiguous in Vt); k_trans deleted. bf16 epilogues repack through LDS
// (row stride 136 to spread banks) for 16-B coalesced stores.
//
// ws layout:
//   [0,       33.5M)  Q        16384x1024 bf16
//   [33.5M,   67.1M)  K        16384x1024 bf16
//   [67.1M,  100.7M)  Vt       8 x 1024x2048 bf16
//   [100.7M, 167.8M)  U        8 x 2048x2048 bf16  (first half aliases xb,
//                                                   dead before U written)
//   [167.8M, 174.1M)  Wb       3 x 1024x1024 bf16
//   [174.1M, ...)     linv     16384 fp32

typedef __bf16 bf16_t;
typedef __bf16 bf16x8 __attribute__((ext_vector_type(8)));
typedef __bf16 bf16x4 __attribute__((ext_vector_type(4)));
typedef float f32x4 __attribute__((ext_vector_type(4)));

__device__ __forceinline__ void gload_lds16(const bf16_t* g, bf16_t* l) {
    __builtin_amdgcn_global_load_lds((const __attribute__((address_space(1))) void*)g,
                                     (__attribute__((address_space(3))) void*)l,
                                     16, 0, 0);
}

// XCD-aware swizzle: blocks sharing an A-strip (same y) get the same lid%8
// (same XCD under round-robin dispatch) and adjacent slots (temporal reuse).
template <int NX, int NY, int LOGNX>
__device__ __forceinline__ void swz_xy(int& x, int& y) {
    const int lid  = blockIdx.x + NX * blockIdx.y;
    const int xcd  = lid & 7;
    const int slot = lid >> 3;
    x = slot & (NX - 1);
    y = xcd * (NY / 8) + (slot >> LOGNX);
}

// ---------------------------------------------------------------------------
// Core GEMM: C[M,N] = A[M,K] @ B[N,K]^T, bf16 row-major K-contiguous.
// Tile 128x128, BK=64, 256 threads (4 waves 2x2), 4x4 16x16x32 MFMAs/wave.
// A staged via global_load_lds; B loaded straight to VGPRs.
// EPI: 0 = (+bias[col]) -> bf16, LDS-repacked vector stores
//      1 = exp(acc*scale) -> bf16, LDS-repacked vector stores
//      2 = acc*aux[row] -> fp32 direct stores
//      3 = (+bias[col]) -> bf16 TRANSPOSED into Vt[b][col][row]
// ---------------------------------------------------------------------------
template <int EPI, int LDA, int LDB>
__device__ __forceinline__ void gemm_bt_core(
    const bf16_t* __restrict__ A,
    const bf16_t* __restrict__ B,
    bf16_t* __restrict__ Cb, float* __restrict__ Cf, int ldc,
    const float* __restrict__ aux, float scale, int K,
    int m0, int n0)
{
    __shared__ bf16_t smem[128 * 136];     // loop: As = first 8192 (16 KB)
    bf16_t* As = smem;                     // epilogue (EPI 0/1): full C repack

    const int t    = threadIdx.x;
    const int lane = t & 63;
    const int wave = t >> 6;
    const int wm   = wave >> 1;
    const int wn   = wave & 1;
    const int lr   = lane & 15;
    const int quad = lane >> 4;

    const int srow   = t >> 3;
    const int schunk = (t & 7) * 8;

    f32x4 acc[4][4];
#pragma unroll
    for (int i = 0; i < 4; i++)
#pragma unroll
        for (int j = 0; j < 4; j++) acc[i][j] = (f32x4){0.f, 0.f, 0.f, 0.f};

    const bf16_t* Ag = A + (size_t)(m0 + srow) * LDA + schunk;
    // per-lane B base: row = n0 + wn*64 + lr, k-chunk = quad*8
    const bf16_t* Bg = B + (size_t)(n0 + wn * 64 + lr) * LDB + quad * 8;

    for (int kt = 0; kt < K; kt += 64) {
#pragma unroll
        for (int j = 0; j < 4; j++)
            gload_lds16(Ag + (size_t)j * 32 * LDA + kt, As + j * 2048 + t * 8);
        // B frags for this kt, straight to regs (drained by the same barrier)
        bf16x8 bfr[2][4];
#pragma unroll
        for (int s = 0; s < 2; s++)
#pragma unroll
            for (int j = 0; j < 4; j++)
                bfr[s][j] = *(const bf16x8*)(Bg + (size_t)j * 16 * LDB + kt + s * 32);
        __syncthreads();

#pragma unroll
        for (int s = 0; s < 2; s++) {
            bf16x8 af[4];
#pragma unroll
            for (int i = 0; i < 4; i++)
                af[i] = *(const bf16x8*)(As + (wm * 64 + i * 16 + lr) * 64 + s * 32 + quad * 8);
#pragma unroll
            for (int i = 0; i < 4; i++)
#pragma unroll
                for (int j = 0; j < 4; j++)
                    acc[i][j] = __builtin_amdgcn_mfma_f32_16x16x32_bf16(af[i], bfr[s][j], acc[i][j], 0, 0, 0);
        }
        __syncthreads();
    }

    // Epilogue. C/D layout: col = lane&15, row = quad*4 + reg.
    if (EPI == 0 || EPI == 1) {
        // stage to LDS (row stride 136 spreads banks), then vector stores
#pragma unroll
        for (int j = 0; j < 4; j++) {
            const int col = wn * 64 + j * 16 + lr;
            const float bv = (EPI == 0) ? aux[n0 + col] : 0.f;
#pragma unroll
            for (int i = 0; i < 4; i++) {
                const int row = wm * 64 + i * 16 + quad * 4;
#pragma unroll
                for (int r = 0; r < 4; r++) {
                    float v = (EPI == 0) ? (acc[i][j][r] + bv)
                                         : __expf(acc[i][j][r] * scale);
                    smem[(row + r) * 136 + col] = (__bf16)v;
                }
            }
        }
        __syncthreads();
        const int lr2  = t >> 1;
        const int half = t & 1;
#pragma unroll
        for (int c8 = 0; c8 < 8; c8++) {
            const int col0 = half * 64 + c8 * 8;
            bf16x8 v = *(const bf16x8*)(smem + lr2 * 136 + col0);
            *(bf16x8*)(Cb + (size_t)(m0 + lr2) * ldc + n0 + col0) = v;
        }
    } else if (EPI == 2) {
#pragma unroll
        for (int i = 0; i < 4; i++) {
            const int row = m0 + wm * 64 + i * 16 + quad * 4;
#pragma unroll
            for (int r = 0; r < 4; r++) {
                const float s = aux[row + r];
                float* crow = Cf + (size_t)(row + r) * ldc + n0 + wn * 64 + lr;
#pragma unroll
                for (int j = 0; j < 4; j++)
                    crow[j * 16] = acc[i][j][r] * s;
            }
        }
    } else {
        // EPI 3: transposed write into Vt[b][col][row], rows global = b*2048+s
#pragma unroll
        for (int j = 0; j < 4; j++) {
            const int col = n0 + wn * 64 + j * 16 + lr;      // d index
            const float bv = aux[col];
#pragma unroll
            for (int i = 0; i < 4; i++) {
                const int rowg = m0 + wm * 64 + i * 16 + quad * 4;  // global s
                const int b    = rowg >> 11;
                const int s    = rowg & 2047;
                bf16x4 p = { (__bf16)(acc[i][j][0] + bv), (__bf16)(acc[i][j][1] + bv),
                             (__bf16)(acc[i][j][2] + bv), (__bf16)(acc[i][j][3] + bv) };
                *(bf16x4*)(Cb + ((size_t)b << 21) + ((size_t)col << 11) + s) = p;
            }
        }
    }
}

// --------------------------- kernel wrappers -------------------------------

__global__ __launch_bounds__(256) void k_qkv(
    const bf16_t* __restrict__ xb, const bf16_t* __restrict__ Wb,
    bf16_t* __restrict__ Q,
    const float* __restrict__ bq, const float* __restrict__ bk)
{
    const int z = blockIdx.z;
    const float* bias = (z == 0) ? bq : bk;
    bf16_t* C = Q + (size_t)z * 16384 * 1024;
    int x, y;
    swz_xy<8, 128, 3>(x, y);
    gemm_bt_core<0, 1024, 1024>(xb, Wb + (size_t)z * 1024 * 1024,
                                C, nullptr, 1024, bias, 0.f, 1024, y * 128, x * 128);
}

__global__ __launch_bounds__(256) void k_qkvV(
    const bf16_t* __restrict__ xb, const bf16_t* __restrict__ Wv,
    bf16_t* __restrict__ Vt, const float* __restrict__ bv)
{
    int x, y;
    swz_xy<8, 128, 3>(x, y);
    gemm_bt_core<3, 1024, 1024>(xb, Wv, Vt, nullptr, 0, bv, 0.f, 1024,
                                y * 128, x * 128);
}

__global__ __launch_bounds__(256) void k_scores(
    const bf16_t* __restrict__ Q, const bf16_t* __restrict__ Km,
    bf16_t* __restrict__ U)
{
    const int b = blockIdx.z;
    int x, y;
    swz_xy<16, 16, 4>(x, y);
    gemm_bt_core<1, 1024, 1024>(Q + (size_t)b * 2048 * 1024,
                                Km + (size_t)b * 2048 * 1024,
                                U + (size_t)b * 2048 * 2048, nullptr, 2048,
                                nullptr, 0.03125f, 1024, y * 128, x * 128);
}

__global__ __launch_bounds__(256) void k_pv(
    const bf16_t* __restrict__ U, const bf16_t* __restrict__ Vt,
    float* __restrict__ Out, const float* __restrict__ linv)
{
    const int b = blockIdx.z;
    int x, y;
    swz_xy<8, 16, 3>(x, y);
    gemm_bt_core<2, 2048, 2048>(U + (size_t)b * 2048 * 2048,
                                Vt + (size_t)b * 1024 * 2048,
                                nullptr, Out + (size_t)b * 2048 * 1024, 1024,
                                linv + b * 2048, 0.f, 2048, y * 128, x * 128);
}

// fp32 -> bf16 conversion, 4 elems/thread, grid-stride
__global__ __launch_bounds__(256) void k_cvt(
    const float* __restrict__ in, bf16_t* __restrict__ out, long ngroups)
{
    long idx    = (long)blockIdx.x * blockDim.x + threadIdx.x;
    long stride = (long)gridDim.x * blockDim.x;
    for (long i = idx; i < ngroups; i += stride) {
        float4 v = ((const float4*)in)[i];
        bf16x4 o = { (__bf16)v.x, (__bf16)v.y, (__bf16)v.z, (__bf16)v.w };
        ((bf16x4*)out)[i] = o;
    }
}

// fused 3-weight fp32 -> bf16 (z selects source)
__global__ __launch_bounds__(256) void k_cvt3(
    const float* __restrict__ w0, const float* __restrict__ w1,
    const float* __restrict__ w2, bf16_t* __restrict__ out)
{
    const int z = blockIdx.z;
    const float* in = (z == 0) ? w0 : (z == 1) ? w1 : w2;
    bf16_t* o = out + (size_t)z * 1048576;
    long i = (long)blockIdx.x * blockDim.x + threadIdx.x;
    float4 v = ((const float4*)in)[i];
    bf16x4 ov = { (__bf16)v.x, (__bf16)v.y, (__bf16)v.z, (__bf16)v.w };
    ((bf16x4*)o)[i] = ov;
}

// linv[row] = 1 / sum_k U[row][k],  K=2048 (one 16B load/thread)
__global__ __launch_bounds__(256) void k_rowsum(
    const bf16_t* __restrict__ U, float* __restrict__ linv)
{
    __shared__ float red[256];
    const int row = blockIdx.x;
    const int t   = threadIdx.x;
    bf16x8 v = *((const bf16x8*)(U + (size_t)row * 2048) + t);
    float s = 0.f;
#pragma unroll
    for (int e = 0; e < 8; e++) s += (float)v[e];
    red[t] = s;
    __syncthreads();
    for (int o = 128; o > 0; o >>= 1) {
        if (t < o) red[t] += red[t + o];
        __syncthreads();
    }
    if (t == 0) linv[row] = 1.0f / red[0];
}

// ---------------------------------------------------------------------------

extern "C" void kernel_launch(void* const* d_in, const int* in_sizes, int n_in,
                              void* d_out, int out_size, void* d_ws, size_t ws_size,
                              hipStream_t stream)
{
    const float* x  = (const float*)d_in[0];
    const float* Wq = (const float*)d_in[1];
    const float* bq = (const float*)d_in[2];
    const float* Wk = (const float*)d_in[3];
    const float* bk = (const float*)d_in[4];
    const float* Wv = (const float*)d_in[5];
    const float* bv = (const float*)d_in[6];

    bf16_t* Q    = (bf16_t*)d_ws;              // 16384x1024
    bf16_t* Km   = Q + 16777216;               // 16384x1024
    bf16_t* Vt   = Km + 16777216;              // 8 x 1024x2048
    bf16_t* U    = Vt + 16777216;              // 8 x 2048x2048
    bf16_t* xb   = U;                          // alias: dead before U written
    bf16_t* Wb   = U + 33554432;               // 3 x 1024x1024
    float*  linv = (float*)(Wb + 3145728);     // 16384

    k_cvt<<<dim3(2048), 256, 0, stream>>>(x, xb, 16777216 / 4);
    k_cvt3<<<dim3(1024, 1, 3), 256, 0, stream>>>(Wq, Wk, Wv, Wb);
    k_qkv<<<dim3(8, 128, 2), 256, 0, stream>>>(xb, Wb, Q, bq, bk);
    k_qkvV<<<dim3(8, 128), 256, 0, stream>>>(xb, Wb + (size_t)2 * 1048576, Vt, bv);
    k_scores<<<dim3(16, 16, 8), 256, 0, stream>>>(Q, Km, U);
    k_rowsum<<<dim3(16384), 256, 0, stream>>>(U, linv);
    k_pv<<<dim3(8, 16, 8), 256, 0, stream>>>(U, Vt, (float*)d_out, linv);
}

// Round 4
// 439.965 us; speedup vs baseline: 1.5311x; 1.5311x over previous
//
#include <hip/hip_runtime.h>
#include <stdint.h>

// Self-attention, B=8, S=2048, D=1024, fp32 in/out, bf16 MFMA compute.
//
// Pipeline:
//   1. cvt: x -> xb (bf16); Wq/Wk/Wv -> Wb (bf16, one fused launch)
//   2. k_qkv  : Q/K = xb @ W^T + b     (z=0,1)    GEMM_BT, bf16 out
//      k_qkvV : Vt = (xb @ Wv^T + bv)^T (direct transposed epilogue)
//   3. memset l=0; k_scores: U = exp((Q @ K^T)/32) bf16, + atomic per-row
//      partial sums into l (scores bounded |s|<=|q||k|/32, no max-sub needed)
//   4. k_pv   : out = (U @ Vt^T) * (1/l[row])  (fp32 out)
//
// R4 changes:
//  - REVERT R3's direct-B (regressed 496->674: per-wave strided B loads
//    fragmented L2 traffic and lost cross-wave sharing). B back through LDS.
//  - XOR k-chunk swizzle on As/Bs. R2 counters showed 3.78e7 conflict-cycles
//    per GEMM dispatch = ~24 extra cyc/ds_read_b128: frag reads at byte
//    128R+64s+16q have bank (16s+4q)%32, independent of row -> 16-way
//    conflict. gload_lds pins the LDS write layout, so instead thread t
//    fetches GLOBAL chunk (t&7)^(srow&7) (same 128-B segment, coalescing
//    kept); reader finds chunk c of row R at slot c^(R&7)=c^(lr&7) -> banks
//    fully spread, only free 2-way aliasing remains.
//  - k_rowsum folded into k_scores epilogue (atomicAdd row partials; l
//    zeroed via hipMemsetAsync, graph-capturable). k_pv multiplies by 1/l.
//
// ws layout:
//   [0,       33.5M)  Q        16384x1024 bf16
//   [33.5M,   67.1M)  K        16384x1024 bf16
//   [67.1M,  100.7M)  Vt       8 x 1024x2048 bf16
//   [100.7M, 167.8M)  U        8 x 2048x2048 bf16  (first half aliases xb,
//                                                   dead before U written)
//   [167.8M, 174.1M)  Wb       3 x 1024x1024 bf16
//   [174.1M, ...)     l        16384 fp32 (attn row sums, atomic)

typedef __bf16 bf16_t;
typedef __bf16 bf16x8 __attribute__((ext_vector_type(8)));
typedef __bf16 bf16x4 __attribute__((ext_vector_type(4)));
typedef float f32x4 __attribute__((ext_vector_type(4)));

__device__ __forceinline__ void gload_lds16(const bf16_t* g, bf16_t* l) {
    __builtin_amdgcn_global_load_lds((const __attribute__((address_space(1))) void*)g,
                                     (__attribute__((address_space(3))) void*)l,
                                     16, 0, 0);
}

// XCD-aware swizzle: blocks sharing an A-strip (same y) get the same lid%8
// (same XCD under round-robin dispatch) and adjacent slots (temporal reuse).
template <int NX, int NY, int LOGNX>
__device__ __forceinline__ void swz_xy(int& x, int& y) {
    const int lid  = blockIdx.x + NX * blockIdx.y;
    const int xcd  = lid & 7;
    const int slot = lid >> 3;
    x = slot & (NX - 1);
    y = xcd * (NY / 8) + (slot >> LOGNX);
}

// ---------------------------------------------------------------------------
// Core GEMM: C[M,N] = A[M,K] @ B[N,K]^T, bf16 row-major K-contiguous.
// Tile 128x128, BK=64, 256 threads (4 waves 2x2), 4x4 16x16x32 MFMAs/wave.
// A and B staged via global_load_lds with XOR k-chunk swizzle (see header).
// EPI: 0 = (+bias[col]) -> bf16, LDS-repacked vector stores
//      1 = exp(acc*scale) -> bf16, LDS-repacked vector stores + atomic row
//          sums into aux
//      2 = acc*(1/aux[row]) -> fp32 direct stores
//      3 = (+bias[col]) -> bf16 TRANSPOSED into Vt[b][col][row]
// ---------------------------------------------------------------------------
template <int EPI, int LDA, int LDB>
__device__ __forceinline__ void gemm_bt_core(
    const bf16_t* __restrict__ A,
    const bf16_t* __restrict__ B,
    bf16_t* __restrict__ Cb, float* __restrict__ Cf, int ldc,
    float* __restrict__ aux, float scale, int K,
    int m0, int n0)
{
    __shared__ bf16_t smem[128 * 136];   // loop: As/Bs = 16384 elems (32 KB)
    bf16_t* As = smem;                   // epilogue (EPI 0/1): C repack 34 KB
    bf16_t* Bs = smem + 8192;

    const int t    = threadIdx.x;
    const int lane = t & 63;
    const int wave = t >> 6;
    const int wm   = wave >> 1;
    const int wn   = wave & 1;
    const int lr   = lane & 15;
    const int quad = lane >> 4;
    const int swz  = lr & 7;             // read-side xor key (= row&7)

    const int srow   = t >> 3;                        // 0..31
    const int schunk = ((t & 7) ^ (srow & 7)) * 8;    // swizzled global chunk

    f32x4 acc[4][4];
#pragma unroll
    for (int i = 0; i < 4; i++)
#pragma unroll
        for (int j = 0; j < 4; j++) acc[i][j] = (f32x4){0.f, 0.f, 0.f, 0.f};

    const bf16_t* Ag = A + (size_t)(m0 + srow) * LDA + schunk;
    const bf16_t* Bg = B + (size_t)(n0 + srow) * LDB + schunk;

    for (int kt = 0; kt < K; kt += 64) {
#pragma unroll
        for (int j = 0; j < 4; j++) {
            gload_lds16(Ag + (size_t)j * 32 * LDA + kt, As + j * 2048 + t * 8);
            gload_lds16(Bg + (size_t)j * 32 * LDB + kt, Bs + j * 2048 + t * 8);
        }
        __syncthreads();

#pragma unroll
        for (int s = 0; s < 2; s++) {
            const int koff = ((s * 4 + quad) ^ swz) * 8;   // swizzled slot
            bf16x8 af[4], bfr[4];
#pragma unroll
            for (int i = 0; i < 4; i++)
                af[i] = *(const bf16x8*)(As + (wm * 64 + i * 16 + lr) * 64 + koff);
#pragma unroll
            for (int j = 0; j < 4; j++)
                bfr[j] = *(const bf16x8*)(Bs + (wn * 64 + j * 16 + lr) * 64 + koff);
#pragma unroll
            for (int i = 0; i < 4; i++)
#pragma unroll
                for (int j = 0; j < 4; j++)
                    acc[i][j] = __builtin_amdgcn_mfma_f32_16x16x32_bf16(af[i], bfr[j], acc[i][j], 0, 0, 0);
        }
        __syncthreads();
    }

    // Epilogue. C/D layout: col = lane&15, row = quad*4 + reg.
    if (EPI == 0 || EPI == 1) {
        // stage to LDS (row stride 136), then 16-B coalesced stores
#pragma unroll
        for (int j = 0; j < 4; j++) {
            const int col = wn * 64 + j * 16 + lr;
            const float bv = (EPI == 0) ? aux[n0 + col] : 0.f;
#pragma unroll
            for (int i = 0; i < 4; i++) {
                const int row = wm * 64 + i * 16 + quad * 4;
#pragma unroll
                for (int r = 0; r < 4; r++) {
                    float v = (EPI == 0) ? (acc[i][j][r] + bv)
                                         : __expf(acc[i][j][r] * scale);
                    smem[(row + r) * 136 + col] = (__bf16)v;
                }
            }
        }
        __syncthreads();
        const int lr2  = t >> 1;       // row 0..127
        const int half = t & 1;        // col half
        float part = 0.f;
#pragma unroll
        for (int c8 = 0; c8 < 8; c8++) {
            const int col0 = half * 64 + c8 * 8;
            bf16x8 v = *(const bf16x8*)(smem + lr2 * 136 + col0);
            *(bf16x8*)(Cb + (size_t)(m0 + lr2) * ldc + n0 + col0) = v;
            if (EPI == 1) {
#pragma unroll
                for (int e = 0; e < 8; e++) part += (float)v[e];
            }
        }
        if (EPI == 1) {
            part += __shfl_xor(part, 1);
            if (half == 0) atomicAdd(aux + m0 + lr2, part);
        }
    } else if (EPI == 2) {
#pragma unroll
        for (int i = 0; i < 4; i++) {
            const int row = m0 + wm * 64 + i * 16 + quad * 4;
#pragma unroll
            for (int r = 0; r < 4; r++) {
                const float s = 1.0f / aux[row + r];
                float* crow = Cf + (size_t)(row + r) * ldc + n0 + wn * 64 + lr;
#pragma unroll
                for (int j = 0; j < 4; j++)
                    crow[j * 16] = acc[i][j][r] * s;
            }
        }
    } else {
        // EPI 3: transposed write into Vt[b][col][row], rows global = b*2048+s
#pragma unroll
        for (int j = 0; j < 4; j++) {
            const int col = n0 + wn * 64 + j * 16 + lr;      // d index
            const float bv = aux[col];
#pragma unroll
            for (int i = 0; i < 4; i++) {
                const int rowg = m0 + wm * 64 + i * 16 + quad * 4;  // global s
                const int b    = rowg >> 11;
                const int s    = rowg & 2047;
                bf16x4 p = { (__bf16)(acc[i][j][0] + bv), (__bf16)(acc[i][j][1] + bv),
                             (__bf16)(acc[i][j][2] + bv), (__bf16)(acc[i][j][3] + bv) };
                *(bf16x4*)(Cb + ((size_t)b << 21) + ((size_t)col << 11) + s) = p;
            }
        }
    }
}

// --------------------------- kernel wrappers -------------------------------

__global__ __launch_bounds__(256) void k_qkv(
    const bf16_t* __restrict__ xb, const bf16_t* __restrict__ Wb,
    bf16_t* __restrict__ Q,
    const float* __restrict__ bq, const float* __restrict__ bk)
{
    const int z = blockIdx.z;
    float* bias = (float*)((z == 0) ? bq : bk);
    bf16_t* C = Q + (size_t)z * 16384 * 1024;
    int x, y;
    swz_xy<8, 128, 3>(x, y);
    gemm_bt_core<0, 1024, 1024>(xb, Wb + (size_t)z * 1024 * 1024,
                                C, nullptr, 1024, bias, 0.f, 1024, y * 128, x * 128);
}

__global__ __launch_bounds__(256) void k_qkvV(
    const bf16_t* __restrict__ xb, const bf16_t* __restrict__ Wv,
    bf16_t* __restrict__ Vt, const float* __restrict__ bv)
{
    int x, y;
    swz_xy<8, 128, 3>(x, y);
    gemm_bt_core<3, 1024, 1024>(xb, Wv, Vt, nullptr, 0, (float*)bv, 0.f, 1024,
                                y * 128, x * 128);
}

__global__ __launch_bounds__(256) void k_scores(
    const bf16_t* __restrict__ Q, const bf16_t* __restrict__ Km,
    bf16_t* __restrict__ U, float* __restrict__ l)
{
    const int b = blockIdx.z;
    int x, y;
    swz_xy<16, 16, 4>(x, y);
    gemm_bt_core<1, 1024, 1024>(Q + (size_t)b * 2048 * 1024,
                                Km + (size_t)b * 2048 * 1024,
                                U + (size_t)b * 2048 * 2048, nullptr, 2048,
                                l + b * 2048, 0.03125f, 1024, y * 128, x * 128);
}

__global__ __launch_bounds__(256) void k_pv(
    const bf16_t* __restrict__ U, const bf16_t* __restrict__ Vt,
    float* __restrict__ Out, float* __restrict__ l)
{
    const int b = blockIdx.z;
    int x, y;
    swz_xy<8, 16, 3>(x, y);
    gemm_bt_core<2, 2048, 2048>(U + (size_t)b * 2048 * 2048,
                                Vt + (size_t)b * 1024 * 2048,
                                nullptr, Out + (size_t)b * 2048 * 1024, 1024,
                                l + b * 2048, 0.f, 2048, y * 128, x * 128);
}

// fp32 -> bf16 conversion, 4 elems/thread, grid-stride
__global__ __launch_bounds__(256) void k_cvt(
    const float* __restrict__ in, bf16_t* __restrict__ out, long ngroups)
{
    long idx    = (long)blockIdx.x * blockDim.x + threadIdx.x;
    long stride = (long)gridDim.x * blockDim.x;
    for (long i = idx; i < ngroups; i += stride) {
        float4 v = ((const float4*)in)[i];
        bf16x4 o = { (__bf16)v.x, (__bf16)v.y, (__bf16)v.z, (__bf16)v.w };
        ((bf16x4*)out)[i] = o;
    }
}

// fused 3-weight fp32 -> bf16 (z selects source)
__global__ __launch_bounds__(256) void k_cvt3(
    const float* __restrict__ w0, const float* __restrict__ w1,
    const float* __restrict__ w2, bf16_t* __restrict__ out)
{
    const int z = blockIdx.z;
    const float* in = (z == 0) ? w0 : (z == 1) ? w1 : w2;
    bf16_t* o = out + (size_t)z * 1048576;
    long i = (long)blockIdx.x * blockDim.x + threadIdx.x;
    float4 v = ((const float4*)in)[i];
    bf16x4 ov = { (__bf16)v.x, (__bf16)v.y, (__bf16)v.z, (__bf16)v.w };
    ((bf16x4*)o)[i] = ov;
}

// ---------------------------------------------------------------------------

extern "C" void kernel_launch(void* const* d_in, const int* in_sizes, int n_in,
                              void* d_out, int out_size, void* d_ws, size_t ws_size,
                              hipStream_t stream)
{
    const float* x  = (const float*)d_in[0];
    const float* Wq = (const float*)d_in[1];
    const float* bq = (const float*)d_in[2];
    const float* Wk = (const float*)d_in[3];
    const float* bk = (const float*)d_in[4];
    const float* Wv = (const float*)d_in[5];
    const float* bv = (const float*)d_in[6];

    bf16_t* Q    = (bf16_t*)d_ws;              // 16384x1024
    bf16_t* Km   = Q + 16777216;               // 16384x1024
    bf16_t* Vt   = Km + 16777216;              // 8 x 1024x2048
    bf16_t* U    = Vt + 16777216;              // 8 x 2048x2048
    bf16_t* xb   = U;                          // alias: dead before U written
    bf16_t* Wb   = U + 33554432;               // 3 x 1024x1024
    float*  l    = (float*)(Wb + 3145728);     // 16384

    k_cvt<<<dim3(2048), 256, 0, stream>>>(x, xb, 16777216 / 4);
    k_cvt3<<<dim3(1024, 1, 3), 256, 0, stream>>>(Wq, Wk, Wv, Wb);
    hipMemsetAsync(l, 0, 16384 * sizeof(float), stream);
    k_qkv<<<dim3(8, 128, 2), 256, 0, stream>>>(xb, Wb, Q, bq, bk);
    k_qkvV<<<dim3(8, 128), 256, 0, stream>>>(xb, Wb + (size_t)2 * 1048576, Vt, bv);
    k_scores<<<dim3(16, 16, 8), 256, 0, stream>>>(Q, Km, U, l);
    k_pv<<<dim3(8, 16, 8), 256, 0, stream>>>(U, Vt, (float*)d_out, l);
}

// Round 5
// 424.921 us; speedup vs baseline: 1.5853x; 1.0354x over previous
//
#include <hip/hip_runtime.h>
#include <stdint.h>

// Self-attention, B=8, S=2048, D=1024, fp32 in/out, bf16 MFMA compute.
//
// Pipeline:
//   1. k_cvt: x -> xb (bf16), zero l;  k_cvt3: Wq/Wk/Wv -> Wb
//   2. k_qkv3 (z=0,1): Q/K = xb @ W^T + b   (z=2): Vt = (xb @ Wv^T + bv)^T
//   3. k_scores: U = exp((Q @ K^T)/32) bf16 + atomic per-row sums into l
//      (scores bounded |s|<=|q||k|/32 -> no max-subtraction needed)
//   4. k_pv   : out = (U @ Vt^T) * (1/l[row])  (fp32 out)
//
// R5 changes:
//  - batch<->XCD pinning for k_scores/k_pv: B=8 == XCDs=8. HW round-robins
//    linear workgroup id across XCDs (xcd = lid&7), so assign work batch
//    b = lid&7: each XCD's working set becomes ONE batch's K (or Vt) = 4 MB
//    = its L2. R4 counters: k_scores FETCH 147 MB vs 67 distinct (K cycled
//    8 batches x 4 MB through each L2 -> thrash).
//  - k_qkv + k_qkvV merged into one z=3 launch (tail overlap, -1 launch),
//    weight slab z' slowest within each XCD so W_z (2 MB) stays L2-pinned.
//  - l zeroed inside k_cvt (memsetAsync launch dropped).
//  - (kept from R4) XOR k-chunk LDS swizzle: bank conflicts measured 0.
//
// ws layout:
//   [0,       33.5M)  Q        16384x1024 bf16
//   [33.5M,   67.1M)  K        16384x1024 bf16
//   [67.1M,  100.7M)  Vt       8 x 1024x2048 bf16
//   [100.7M, 167.8M)  U        8 x 2048x2048 bf16  (first half aliases xb,
//                                                   dead before U written)
//   [167.8M, 174.1M)  Wb       3 x 1024x1024 bf16
//   [174.1M, ...)     l        16384 fp32 (attn row sums, atomic)

typedef __bf16 bf16_t;
typedef __bf16 bf16x8 __attribute__((ext_vector_type(8)));
typedef __bf16 bf16x4 __attribute__((ext_vector_type(4)));
typedef float f32x4 __attribute__((ext_vector_type(4)));

__device__ __forceinline__ void gload_lds16(const bf16_t* g, bf16_t* l) {
    __builtin_amdgcn_global_load_lds((const __attribute__((address_space(1))) void*)g,
                                     (__attribute__((address_space(3))) void*)l,
                                     16, 0, 0);
}

// ---------------------------------------------------------------------------
// Core GEMM: C[M,N] = A[M,K] @ B[N,K]^T, bf16 row-major K-contiguous.
// Tile 128x128, BK=64, 256 threads (4 waves 2x2), 4x4 16x16x32 MFMAs/wave.
// A and B staged via global_load_lds with XOR k-chunk swizzle (conflict-free,
// measured SQ_LDS_BANK_CONFLICT = 0).
// EPI: 0 = (+bias[col]) -> bf16, LDS-repacked vector stores
//      1 = exp(acc*scale) -> bf16, LDS-repacked vector stores + atomic row
//          sums into aux
//      2 = acc*(1/aux[row]) -> fp32 direct stores
//      3 = (+bias[col]) -> bf16 TRANSPOSED into Vt[b][col][row]
// ---------------------------------------------------------------------------
template <int EPI, int LDA, int LDB>
__device__ __forceinline__ void gemm_bt_core(
    const bf16_t* __restrict__ A,
    const bf16_t* __restrict__ B,
    bf16_t* __restrict__ Cb, float* __restrict__ Cf, int ldc,
    float* __restrict__ aux, float scale, int K,
    int m0, int n0)
{
    __shared__ bf16_t smem[128 * 136];   // loop: As/Bs = 16384 elems (32 KB)
    bf16_t* As = smem;                   // epilogue (EPI 0/1): C repack 34 KB
    bf16_t* Bs = smem + 8192;

    const int t    = threadIdx.x;
    const int lane = t & 63;
    const int wave = t >> 6;
    const int wm   = wave >> 1;
    const int wn   = wave & 1;
    const int lr   = lane & 15;
    const int quad = lane >> 4;
    const int swz  = lr & 7;             // read-side xor key (= row&7)

    const int srow   = t >> 3;                        // 0..31
    const int schunk = ((t & 7) ^ (srow & 7)) * 8;    // swizzled global chunk

    f32x4 acc[4][4];
#pragma unroll
    for (int i = 0; i < 4; i++)
#pragma unroll
        for (int j = 0; j < 4; j++) acc[i][j] = (f32x4){0.f, 0.f, 0.f, 0.f};

    const bf16_t* Ag = A + (size_t)(m0 + srow) * LDA + schunk;
    const bf16_t* Bg = B + (size_t)(n0 + srow) * LDB + schunk;

    for (int kt = 0; kt < K; kt += 64) {
#pragma unroll
        for (int j = 0; j < 4; j++) {
            gload_lds16(Ag + (size_t)j * 32 * LDA + kt, As + j * 2048 + t * 8);
            gload_lds16(Bg + (size_t)j * 32 * LDB + kt, Bs + j * 2048 + t * 8);
        }
        __syncthreads();

#pragma unroll
        for (int s = 0; s < 2; s++) {
            const int koff = ((s * 4 + quad) ^ swz) * 8;   // swizzled slot
            bf16x8 af[4], bfr[4];
#pragma unroll
            for (int i = 0; i < 4; i++)
                af[i] = *(const bf16x8*)(As + (wm * 64 + i * 16 + lr) * 64 + koff);
#pragma unroll
            for (int j = 0; j < 4; j++)
                bfr[j] = *(const bf16x8*)(Bs + (wn * 64 + j * 16 + lr) * 64 + koff);
#pragma unroll
            for (int i = 0; i < 4; i++)
#pragma unroll
                for (int j = 0; j < 4; j++)
                    acc[i][j] = __builtin_amdgcn_mfma_f32_16x16x32_bf16(af[i], bfr[j], acc[i][j], 0, 0, 0);
        }
        __syncthreads();
    }

    // Epilogue. C/D layout: col = lane&15, row = quad*4 + reg.
    if (EPI == 0 || EPI == 1) {
        // stage to LDS (row stride 136), then 16-B coalesced stores
#pragma unroll
        for (int j = 0; j < 4; j++) {
            const int col = wn * 64 + j * 16 + lr;
            const float bv = (EPI == 0) ? aux[n0 + col] : 0.f;
#pragma unroll
            for (int i = 0; i < 4; i++) {
                const int row = wm * 64 + i * 16 + quad * 4;
#pragma unroll
                for (int r = 0; r < 4; r++) {
                    float v = (EPI == 0) ? (acc[i][j][r] + bv)
                                         : __expf(acc[i][j][r] * scale);
                    smem[(row + r) * 136 + col] = (__bf16)v;
                }
            }
        }
        __syncthreads();
        const int lr2  = t >> 1;       // row 0..127
        const int half = t & 1;        // col half
        float part = 0.f;
#pragma unroll
        for (int c8 = 0; c8 < 8; c8++) {
            const int col0 = half * 64 + c8 * 8;
            bf16x8 v = *(const bf16x8*)(smem + lr2 * 136 + col0);
            *(bf16x8*)(Cb + (size_t)(m0 + lr2) * ldc + n0 + col0) = v;
            if (EPI == 1) {
#pragma unroll
                for (int e = 0; e < 8; e++) part += (float)v[e];
            }
        }
        if (EPI == 1) {
            part += __shfl_xor(part, 1);
            if (half == 0) atomicAdd(aux + m0 + lr2, part);
        }
    } else if (EPI == 2) {
#pragma unroll
        for (int i = 0; i < 4; i++) {
            const int row = m0 + wm * 64 + i * 16 + quad * 4;
#pragma unroll
            for (int r = 0; r < 4; r++) {
                const float s = 1.0f / aux[row + r];
                float* crow = Cf + (size_t)(row + r) * ldc + n0 + wn * 64 + lr;
#pragma unroll
                for (int j = 0; j < 4; j++)
                    crow[j * 16] = acc[i][j][r] * s;
            }
        }
    } else {
        // EPI 3: transposed write into Vt[b][col][row], rows global = b*2048+s
#pragma unroll
        for (int j = 0; j < 4; j++) {
            const int col = n0 + wn * 64 + j * 16 + lr;      // d index
            const float bv = aux[col];
#pragma unroll
            for (int i = 0; i < 4; i++) {
                const int rowg = m0 + wm * 64 + i * 16 + quad * 4;  // global s
                const int b    = rowg >> 11;
                const int s    = rowg & 2047;
                bf16x4 p = { (__bf16)(acc[i][j][0] + bv), (__bf16)(acc[i][j][1] + bv),
                             (__bf16)(acc[i][j][2] + bv), (__bf16)(acc[i][j][3] + bv) };
                *(bf16x4*)(Cb + ((size_t)b << 21) + ((size_t)col << 11) + s) = p;
            }
        }
    }
}

// --------------------------- kernel wrappers -------------------------------

// Q/K/Vt projection, grid (8,128,3). xcd = lid&7; within an XCD, x' (weight
// n-tile) fast, y' (A-strip) middle, z' (which matrix) slowest -> W_z (2 MB)
// L2-pinned per phase, xb strips read via L2/L3.
__global__ __launch_bounds__(256) void k_qkv3(
    const bf16_t* __restrict__ xb, const bf16_t* __restrict__ Wb,
    bf16_t* __restrict__ Q, bf16_t* __restrict__ Vt,
    const float* __restrict__ bq, const float* __restrict__ bk,
    const float* __restrict__ bv)
{
    const int lid  = blockIdx.x + 8 * blockIdx.y + 1024 * blockIdx.z;
    const int xcd  = lid & 7;
    const int slot = lid >> 3;          // 0..383
    const int z    = slot >> 7;         // 0..2, slowest
    const int rem  = slot & 127;
    const int xt   = rem & 7;           // fast
    const int yt   = xcd * 16 + (rem >> 3);
    if (z < 2) {
        float* bias = (float*)((z == 0) ? bq : bk);
        gemm_bt_core<0, 1024, 1024>(xb, Wb + (size_t)z * 1048576,
                                    Q + (size_t)z * 16777216, nullptr, 1024,
                                    bias, 0.f, 1024, yt * 128, xt * 128);
    } else {
        gemm_bt_core<3, 1024, 1024>(xb, Wb + (size_t)2 * 1048576,
                                    Vt, nullptr, 0,
                                    (float*)bv, 0.f, 1024, yt * 128, xt * 128);
    }
}

// scores, grid (16,16,8): batch = lid&7 == XCD -> per-XCD working set is one
// batch's K matrix (4 MB = L2). Within XCD: x-tile fast (K sweep), Q-strip
// pinned per y-tile.
__global__ __launch_bounds__(256) void k_scores(
    const bf16_t* __restrict__ Q, const bf16_t* __restrict__ Km,
    bf16_t* __restrict__ U, float* __restrict__ l)
{
    const int lid = blockIdx.x + 16 * blockIdx.y + 256 * blockIdx.z;
    const int b   = lid & 7;
    const int si  = lid >> 3;           // 0..255
    const int xt  = si & 15;
    const int yt  = si >> 4;
    gemm_bt_core<1, 1024, 1024>(Q + (size_t)b * 2048 * 1024,
                                Km + (size_t)b * 2048 * 1024,
                                U + (size_t)b * 2048 * 2048, nullptr, 2048,
                                l + b * 2048, 0.03125f, 1024,
                                yt * 128, xt * 128);
}

// PV, grid (8,16,8): batch = lid&7 == XCD -> per-XCD working set is one
// batch's Vt (4 MB = L2). x-tile (Vt d-slab) fast, U-strip pinned per y-tile.
__global__ __launch_bounds__(256) void k_pv(
    const bf16_t* __restrict__ U, const bf16_t* __restrict__ Vt,
    float* __restrict__ Out, float* __restrict__ l)
{
    const int lid = blockIdx.x + 8 * blockIdx.y + 128 * blockIdx.z;
    const int b   = lid & 7;
    const int si  = lid >> 3;           // 0..127
    const int xt  = si & 7;
    const int yt  = si >> 3;
    gemm_bt_core<2, 2048, 2048>(U + (size_t)b * 2048 * 2048,
                                Vt + (size_t)b * 1024 * 2048,
                                nullptr, Out + (size_t)b * 2048 * 1024, 1024,
                                l + b * 2048, 0.f, 2048,
                                yt * 128, xt * 128);
}

// fp32 -> bf16 conversion, 4 elems/thread; also zeroes l (16384 floats)
__global__ __launch_bounds__(256) void k_cvt(
    const float* __restrict__ in, bf16_t* __restrict__ out, long ngroups,
    float* __restrict__ l)
{
    long idx    = (long)blockIdx.x * blockDim.x + threadIdx.x;
    long stride = (long)gridDim.x * blockDim.x;
    if (blockIdx.x < 64) l[blockIdx.x * 256 + threadIdx.x] = 0.f;
    for (long i = idx; i < ngroups; i += stride) {
        float4 v = ((const float4*)in)[i];
        bf16x4 o = { (__bf16)v.x, (__bf16)v.y, (__bf16)v.z, (__bf16)v.w };
        ((bf16x4*)out)[i] = o;
    }
}

// fused 3-weight fp32 -> bf16 (z selects source)
__global__ __launch_bounds__(256) void k_cvt3(
    const float* __restrict__ w0, const float* __restrict__ w1,
    const float* __restrict__ w2, bf16_t* __restrict__ out)
{
    const int z = blockIdx.z;
    const float* in = (z == 0) ? w0 : (z == 1) ? w1 : w2;
    bf16_t* o = out + (size_t)z * 1048576;
    long i = (long)blockIdx.x * blockDim.x + threadIdx.x;
    float4 v = ((const float4*)in)[i];
    bf16x4 ov = { (__bf16)v.x, (__bf16)v.y, (__bf16)v.z, (__bf16)v.w };
    ((bf16x4*)o)[i] = ov;
}

// ---------------------------------------------------------------------------

extern "C" void kernel_launch(void* const* d_in, const int* in_sizes, int n_in,
                              void* d_out, int out_size, void* d_ws, size_t ws_size,
                              hipStream_t stream)
{
    const float* x  = (const float*)d_in[0];
    const float* Wq = (const float*)d_in[1];
    const float* bq = (const float*)d_in[2];
    const float* Wk = (const float*)d_in[3];
    const float* bk = (const float*)d_in[4];
    const float* Wv = (const float*)d_in[5];
    const float* bv = (const float*)d_in[6];

    bf16_t* Q    = (bf16_t*)d_ws;              // 16384x1024
    bf16_t* Km   = Q + 16777216;               // 16384x1024
    bf16_t* Vt   = Km + 16777216;              // 8 x 1024x2048
    bf16_t* U    = Vt + 16777216;              // 8 x 2048x2048
    bf16_t* xb   = U;                          // alias: dead before U written
    bf16_t* Wb   = U + 33554432;               // 3 x 1024x1024
    float*  l    = (float*)(Wb + 3145728);     // 16384

    k_cvt<<<dim3(2048), 256, 0, stream>>>(x, xb, 16777216 / 4, l);
    k_cvt3<<<dim3(1024, 1, 3), 256, 0, stream>>>(Wq, Wk, Wv, Wb);
    k_qkv3<<<dim3(8, 128, 3), 256, 0, stream>>>(xb, Wb, Q, Vt, bq, bk, bv);
    k_scores<<<dim3(16, 16, 8), 256, 0, stream>>>(Q, Km, U, l);
    k_pv<<<dim3(8, 16, 8), 256, 0, stream>>>(U, Vt, (float*)d_out, l);
}